// Round 17
// baseline (1901.275 us; speedup 1.0000x reference)
//
#include <hip/hip_runtime.h>
#include <hip/hip_bf16.h>
#include <cstdint>
#include <cstddef>

#define B_ 8
#define T_ 2048
#define C_ 2048
#define A_ 2048
#define H_ 32
#define BT_ (B_*T_)

typedef short short8 __attribute__((ext_vector_type(8)));
typedef _Float16 half8 __attribute__((ext_vector_type(8)));
typedef float floatx4 __attribute__((ext_vector_type(4)));

__device__ __forceinline__ unsigned short f2bf(float f) {
  union { float f; uint32_t u; } a; a.f = f;
  uint32_t r = a.u + 0x7fffu + ((a.u >> 16) & 1u);   // RNE
  return (unsigned short)(r >> 16);
}
__device__ __forceinline__ float bf2f(unsigned short s) {
  union { uint32_t u; float f; } a; a.u = ((uint32_t)s) << 16;
  return a.f;
}
__device__ __forceinline__ unsigned short f2h(float f) {
  union { _Float16 h; unsigned short u; } c; c.h = (_Float16)f; return c.u;
}
__device__ __forceinline__ float h2f(unsigned short u) {
  union { unsigned short u; _Float16 h; } c; c.u = u; return (float)c.h;
}
__device__ __forceinline__ void split_hl(float v, unsigned short& hh, unsigned short& ll) {
  hh = f2bf(v);
  ll = f2bf(v - bf2f(hh));
}
// XOR-swizzled index into a row-major [64][64] bf16 LDS tile (G4 recipe)
__device__ __forceinline__ int swz(int row, int col) {
  return row * 64 + (col ^ ((row & 7) << 3));
}
__device__ __forceinline__ short8 ldfrag(const unsigned short* M, int row, int col8) {
  return *(const short8*)&M[row * 64 + (col8 ^ ((row & 7) << 3))];
}

// ---------------- weight prep: f32 -> f16 ----------------
__global__ void conv_f16(const float* __restrict__ s, unsigned short* __restrict__ d, int n) {
  int i = blockIdx.x * 256 + threadIdx.x;
  if (i < n) d[i] = f2h(s[i]);
}

// src (2048 x NV) f32 -> dst (NP x 2048) f16, rows >= NV zero-padded
__global__ void transpose_pad(const float* __restrict__ s, unsigned short* __restrict__ d, int NP, int NV) {
  int i = blockIdx.x * 256 + threadIdx.x;  // over NP*2048
  int n = i >> 11, kk = i & 2047;
  if (n < NP) d[i] = (n < NV) ? f2h(s[kk * NV + n]) : (unsigned short)0;
}

// w2 (5,32,C) f32 -> w2T (5,C,32) f16 (read-coalesced; scattered writes L2-absorbed)
__global__ void transpose_w2(const float* __restrict__ s, unsigned short* __restrict__ d) {
  int i = blockIdx.x * 256 + threadIdx.x;   // over 5*32*2048
  int f = i >> 16, rem = i & 65535;
  int dd = rem >> 11, c = rem & 2047;
  d[((size_t)(f * 2048 + c) << 5) + dd] = f2h(s[((size_t)(f * 32 + dd) << 11) + c]);
}

// ---------------- token shift + maa_x mix (f16 out) + f16 copy of x ----------------
__global__ void shift_mix(const float* __restrict__ x, const float* __restrict__ tmx,
                          unsigned short* __restrict__ xxx, unsigned short* __restrict__ x16) {
  size_t i4 = (size_t)blockIdx.x * 256 + threadIdx.x;   // over BT*C/4
  size_t i = i4 * 4;
  int c = (int)(i & 2047);
  int t = (int)((i >> 11) & 2047);
  float4 xv = *(const float4*)&x[i];
  float4 pv = make_float4(0.f, 0.f, 0.f, 0.f);
  if (t > 0) pv = *(const float4*)&x[i - 2048];
  float4 tv = *(const float4*)&tmx[c];
  ushort4 m;
  m.x = f2h(xv.x + (pv.x - xv.x) * tv.x);
  m.y = f2h(xv.y + (pv.y - xv.y) * tv.y);
  m.z = f2h(xv.z + (pv.z - xv.z) * tv.z);
  m.w = f2h(xv.w + (pv.w - xv.w) * tv.w);
  *(ushort4*)&xxx[i] = m;
  ushort4 xh;
  xh.x = f2h(xv.x); xh.y = f2h(xv.y); xh.z = f2h(xv.z); xh.w = f2h(xv.w);
  *(ushort4*)&x16[i] = xh;
}

// ---------------- async global->LDS helper ----------------
__device__ __forceinline__ void gll16(const void* g, void* l) {
  __builtin_amdgcn_global_load_lds(
      (const __attribute__((address_space(1))) void*)g,
      (__attribute__((address_space(3))) void*)l, 16, 0, 0);
}

// ---------------- f16 GEMM, 128^2 tile (small-N lora paths): C = A * B^T ----------------
// EPI: 0 = ->bf16, 1 = silu->f16, 2 = tanh->f32, 3 = ->f32, 4 = tanh->f16
template<int EPI>
__global__ __launch_bounds__(256)
void gemm_f16(const unsigned short* __restrict__ Am, const unsigned short* __restrict__ Bm,
              void* __restrict__ Cp, int M, int N, int K) {
  __shared__ unsigned short As[128 * 32];
  __shared__ unsigned short Bs[128 * 32];
  const int tid = threadIdx.x;
  const int wid = tid >> 6, lane = tid & 63;
  const int quad = lane >> 4, l15 = lane & 15;
  const long bm = (long)blockIdx.x * 128, bn = (long)blockIdx.y * 128;
  const int wm = (wid & 1) * 64, wn = (wid >> 1) * 64;

  floatx4 acc[4][4];
#pragma unroll
  for (int a = 0; a < 4; a++)
#pragma unroll
    for (int b = 0; b < 4; b++) { floatx4 z = {0.f, 0.f, 0.f, 0.f}; acc[a][b] = z; }

  const int stg_row = wid * 32 + (lane >> 2);
  const int stg_k   = (lane & 3) * 8;
  const int stg_lds = wid * 1024 + lane * 8;

  for (int k0 = 0; k0 < K; k0 += 32) {
    __syncthreads();
#pragma unroll
    for (int p = 0; p < 2; ++p) {
      gll16(Am + (bm + stg_row + p * 16) * (long)K + k0 + stg_k, &As[stg_lds + p * 512]);
      gll16(Bm + (bn + stg_row + p * 16) * (long)K + k0 + stg_k, &Bs[stg_lds + p * 512]);
    }
    __syncthreads();

    half8 af[4], bfr[4];
#pragma unroll
    for (int mi = 0; mi < 4; mi++) af[mi] = *(const half8*)&As[(wm + mi * 16 + l15) * 32 + quad * 8];
#pragma unroll
    for (int ni = 0; ni < 4; ni++) bfr[ni] = *(const half8*)&Bs[(wn + ni * 16 + l15) * 32 + quad * 8];
#pragma unroll
    for (int mi = 0; mi < 4; mi++)
#pragma unroll
      for (int ni = 0; ni < 4; ni++)
        acc[mi][ni] = __builtin_amdgcn_mfma_f32_16x16x32_f16(af[mi], bfr[ni], acc[mi][ni], 0, 0, 0);
  }

#pragma unroll
  for (int mi = 0; mi < 4; mi++)
#pragma unroll
    for (int ni = 0; ni < 4; ni++)
#pragma unroll
      for (int vv = 0; vv < 4; ++vv) {
        long row = bm + wm + mi * 16 + quad * 4 + vv;
        long col = bn + wn + ni * 16 + l15;
        float val = acc[mi][ni][vv];
        if (EPI == 0) {
          ((unsigned short*)Cp)[row * N + col] = f2bf(val);
        } else if (EPI == 1) {
          float s = val / (1.f + __expf(-val));
          ((unsigned short*)Cp)[row * N + col] = f2h(s);
        } else if (EPI == 2) {
          ((float*)Cp)[row * N + col] = tanhf(val);
        } else if (EPI == 4) {
          ((unsigned short*)Cp)[row * N + col] = f2h(tanhf(val));
        } else {
          ((float*)Cp)[row * N + col] = val;
        }
      }
}

// ---------------- f16 GEMM, 256^2 tile, BK=32, 4-buffer counted-vmcnt pipeline ----------------
// v15 swizzle: key ((r>>1)&3) -> conflict-free frag reads (2-way = free, m136)
// EPI: 0 = ->bf16, 1 = silu->f16, 3 = ->f32, 5 = ->f16
template<int EPI>
__global__ __launch_bounds__(512, 2)
void gemm256(const unsigned short* __restrict__ Am, const unsigned short* __restrict__ Bm,
             void* __restrict__ Cp, int M, int N, int K) {
  __shared__ unsigned short At[4][8192];
  __shared__ unsigned short Bt[4][8192];
  const int tid = threadIdx.x;
  const int w = tid >> 6, lane = tid & 63;
  const int quad = lane >> 4, l15 = lane & 15;
  const long bm = (long)blockIdx.x * 256, bn = (long)blockIdx.y * 256;
  const int wm = (w & 1) * 128, wn = (w >> 1) * 64;

  floatx4 acc[8][4];
#pragma unroll
  for (int a = 0; a < 8; a++)
#pragma unroll
    for (int b = 0; b < 4; b++) { floatx4 z = {0.f, 0.f, 0.f, 0.f}; acc[a][b] = z; }

  int srow[2], scol[2];
#pragma unroll
  for (int u = 0; u < 2; ++u) {
    int p = u * 8192 + tid * 16;
    int l = p ^ (((p >> 7) & 3) << 4);
    srow[u] = l >> 6;
    scol[u] = (l & 63) >> 1;
  }
  const int ldst = tid * 16;   // byte offset of this thread's 16B within a unit

  const int NT = K >> 5;
  for (int t = 0; t < 3; ++t) {
#pragma unroll
    for (int u = 0; u < 2; ++u) {
      gll16(Am + (bm + srow[u]) * (long)K + (t << 5) + scol[u],
            (char*)&At[t][0] + u * 8192 + ldst);
      gll16(Bm + (bn + srow[u]) * (long)K + (t << 5) + scol[u],
            (char*)&Bt[t][0] + u * 8192 + ldst);
    }
  }
  asm volatile("s_waitcnt vmcnt(8) lgkmcnt(0)\n\ts_barrier" ::: "memory");

  for (int t = 0; t < NT; ++t) {
    const int bi = t & 3;
    const unsigned short* Ab = At[bi];
    const unsigned short* Bb = Bt[bi];
    const int tn = t + 3;
    const bool do_stage = tn < NT;
    const int bj = tn & 3;

    if (do_stage) {
      gll16(Am + (bm + srow[0]) * (long)K + (tn << 5) + scol[0], (char*)&At[bj][0] + ldst);
      gll16(Bm + (bn + srow[0]) * (long)K + (tn << 5) + scol[0], (char*)&Bt[bj][0] + ldst);
    }
    half8 bfr[4], af[4];
#pragma unroll
    for (int ni = 0; ni < 4; ++ni) {
      int r = wn + ni * 16 + l15;
      bfr[ni] = *(const half8*)((const char*)Bb + r * 64 + ((quad ^ ((r >> 1) & 3)) << 4));
    }
#pragma unroll
    for (int mi = 0; mi < 4; ++mi) {
      int r = wm + mi * 16 + l15;
      af[mi] = *(const half8*)((const char*)Ab + r * 64 + ((quad ^ ((r >> 1) & 3)) << 4));
    }
    __builtin_amdgcn_s_setprio(1);
#pragma unroll
    for (int mi = 0; mi < 4; ++mi)
#pragma unroll
      for (int ni = 0; ni < 4; ++ni)
        acc[mi][ni] = __builtin_amdgcn_mfma_f32_16x16x32_f16(af[mi], bfr[ni], acc[mi][ni], 0, 0, 0);
    __builtin_amdgcn_s_setprio(0);

    if (do_stage) {
      gll16(Am + (bm + srow[1]) * (long)K + (tn << 5) + scol[1], (char*)&At[bj][0] + 8192 + ldst);
      gll16(Bm + (bn + srow[1]) * (long)K + (tn << 5) + scol[1], (char*)&Bt[bj][0] + 8192 + ldst);
    }
#pragma unroll
    for (int mi = 0; mi < 4; ++mi) {
      int r = wm + 64 + mi * 16 + l15;
      af[mi] = *(const half8*)((const char*)Ab + r * 64 + ((quad ^ ((r >> 1) & 3)) << 4));
    }
    __builtin_amdgcn_s_setprio(1);
#pragma unroll
    for (int mi = 0; mi < 4; ++mi)
#pragma unroll
      for (int ni = 0; ni < 4; ++ni)
        acc[4 + mi][ni] = __builtin_amdgcn_mfma_f32_16x16x32_f16(af[mi], bfr[ni], acc[4 + mi][ni], 0, 0, 0);
    __builtin_amdgcn_s_setprio(0);

    asm volatile("s_waitcnt vmcnt(8) lgkmcnt(0)\n\ts_barrier" ::: "memory");
  }

#pragma unroll
  for (int p = 0; p < 2; ++p)
#pragma unroll
    for (int mi = 0; mi < 4; ++mi)
#pragma unroll
      for (int ni = 0; ni < 4; ++ni)
#pragma unroll
        for (int vv = 0; vv < 4; ++vv) {
          long row = bm + wm + p * 64 + mi * 16 + quad * 4 + vv;
          long col = bn + wn + ni * 16 + l15;
          float val = acc[p * 4 + mi][ni][vv];
          if (EPI == 0) {
            ((unsigned short*)Cp)[row * N + col] = f2bf(val);
          } else if (EPI == 1) {
            float s = val / (1.f + __expf(-val));
            ((unsigned short*)Cp)[row * N + col] = f2h(s);
          } else if (EPI == 5) {
            ((unsigned short*)Cp)[row * N + col] = f2h(val);
          } else {
            ((float*)Cp)[row * N + col] = val;
          }
        }
}

// ---------------- MFMA LoRA-mix, f on blockIdx.z; fully-coalesced epilogue ----------------
// v16 (proven): delta staged to LDS zs[128][136]; write-out re-tiled to short8
// full-line streams (no RMW, no read amplification).
__global__ __launch_bounds__(256)
void mix_gemm(const unsigned short* __restrict__ m5f, const unsigned short* __restrict__ w2T,
              const unsigned short* __restrict__ x16,
              const float* __restrict__ tmw, const float* __restrict__ tmk,
              const float* __restrict__ tmv, const float* __restrict__ tmr,
              const float* __restrict__ tmg,
              unsigned short* __restrict__ xw, unsigned short* __restrict__ xk,
              unsigned short* __restrict__ xv, unsigned short* __restrict__ xr,
              unsigned short* __restrict__ xg) {
  __shared__ unsigned short As[128 * 32];
  __shared__ unsigned short Bs[128 * 32];
  __shared__ unsigned short zs[128 * 136];   // padded lora-delta tile (f16)
  const int tid = threadIdx.x;
  const int wid = tid >> 6, lane = tid & 63;
  const int quad = lane >> 4, l15 = lane & 15;
  const long bm = (long)blockIdx.x * 128, bn = (long)blockIdx.y * 128;
  const int f = blockIdx.z;
  const int wm = (wid & 1) * 64, wn = (wid >> 1) * 64;

  const float* tmf = (f == 0) ? tmw : (f == 1) ? tmk : (f == 2) ? tmv : (f == 3) ? tmr : tmg;
  unsigned short* outf = (f == 0) ? xw : (f == 1) ? xk : (f == 2) ? xv : (f == 3) ? xr : xg;

  const int stg_row = wid * 32 + (lane >> 2);
  const int stg_k   = (lane & 3) * 8;
  const int stg_lds = wid * 1024 + lane * 8;

#pragma unroll
  for (int p = 0; p < 2; ++p) {
    gll16(m5f + (bm + stg_row + p * 16) * 256 + f * 32 + stg_k, &As[stg_lds + p * 512]);
    gll16(w2T + ((long)f * 2048 + bn + stg_row + p * 16) * 32 + stg_k, &Bs[stg_lds + p * 512]);
  }
  __syncthreads();

  half8 af[4], bfr[4];
#pragma unroll
  for (int mi = 0; mi < 4; mi++) af[mi] = *(const half8*)&As[(wm + mi * 16 + l15) * 32 + quad * 8];
#pragma unroll
  for (int ni = 0; ni < 4; ni++) bfr[ni] = *(const half8*)&Bs[(wn + ni * 16 + l15) * 32 + quad * 8];

  floatx4 acc[4][4];
#pragma unroll
  for (int a = 0; a < 4; a++)
#pragma unroll
    for (int b = 0; b < 4; b++) { floatx4 z = {0.f, 0.f, 0.f, 0.f}; acc[a][b] = z; }
#pragma unroll
  for (int mi = 0; mi < 4; mi++)
#pragma unroll
    for (int ni = 0; ni < 4; ni++)
      acc[mi][ni] = __builtin_amdgcn_mfma_f32_16x16x32_f16(af[mi], bfr[ni], acc[mi][ni], 0, 0, 0);

  // stage delta to LDS
#pragma unroll
  for (int mi = 0; mi < 4; mi++)
#pragma unroll
    for (int ni = 0; ni < 4; ni++)
#pragma unroll
      for (int vv = 0; vv < 4; ++vv)
        zs[(wm + mi * 16 + quad * 4 + vv) * 136 + wn + ni * 16 + l15] = f2h(acc[mi][ni][vv]);
  __syncthreads();

  // write-out: thread -> (row = pass*16 + tid>>4, cols (tid&15)*8 .. +8)
#pragma unroll
  for (int pass = 0; pass < 8; ++pass) {
    const int row = pass * 16 + (tid >> 4);
    const int c8 = (tid & 15) * 8;
    const long grow = bm + row;
    const size_t gidx = (size_t)grow * 2048 + bn + c8;
    short8 xv8 = *(const short8*)&x16[gidx];
    short8 xp8;
    if ((grow & 2047) > 0) xp8 = *(const short8*)&x16[gidx - 2048];
    else { short8 zz = {0, 0, 0, 0, 0, 0, 0, 0}; xp8 = zz; }
    short8 d8 = *(const short8*)&zs[row * 136 + c8];
    short8 o8;
#pragma unroll
    for (int j = 0; j < 8; ++j) {
      float xc = h2f((unsigned short)xv8[j]);
      float xp = ((grow & 2047) > 0) ? h2f((unsigned short)xp8[j]) : 0.f;
      float tv = tmf[bn + c8 + j];
      o8[j] = (short)f2h(xc + (xp - xc) * (tv + h2f((unsigned short)d8[j])));
    }
    *(short8*)&outf[gidx] = o8;
  }
}

// ---------------- decay: dec = exp(-exp(td + t1 @ decay_w2)) (f32) ----------------
__global__ __launch_bounds__(256)
void decay_kernel(const float* __restrict__ t1, const float* __restrict__ w2d,
                  const float* __restrict__ td, float* __restrict__ dec) {
  const int bt0 = blockIdx.x * 16;
  const int tid = threadIdx.x;
  for (int cc = 0; cc < 8; ++cc) {
    const int a = cc * 256 + tid;
    const float tda = td[a];
    float acc[16];
#pragma unroll
    for (int b = 0; b < 16; b++) acc[b] = 0.f;
    for (int dc = 0; dc < 16; ++dc) {
      float wv0 = w2d[((size_t)(dc * 4 + 0) << 11) + a];
      float wv1 = w2d[((size_t)(dc * 4 + 1) << 11) + a];
      float wv2 = w2d[((size_t)(dc * 4 + 2) << 11) + a];
      float wv3 = w2d[((size_t)(dc * 4 + 3) << 11) + a];
#pragma unroll
      for (int b = 0; b < 16; b++) {
        float4 mv = *(const float4*)&t1[((size_t)(bt0 + b) << 7) + dc * 4];
        acc[b] += mv.x * wv0 + mv.y * wv1 + mv.z * wv2 + mv.w * wv3;
      }
    }
#pragma unroll
    for (int b = 0; b < 16; b++) {
      dec[((size_t)(bt0 + b) << 11) + a] = __expf(-__expf(tda + acc[b]));
    }
  }
}

// ---------------- WKV6 chunk-parallel (MFMA) + fused GroupNorm*g, 8 waves ----------------
// v16 structure (proven 262us): 4 barriers/chunk; S as bf16 hi/lo pair only;
// S-update deferred post-B4; merged phase 2+4a; g prefetch after B3.
// v18: v read as f16 (was f32) — halves v traffic; v is split to bf16 hi/lo
// internally anyway, and r is already bf16, so f16 v is precision-safe.
template<int KF32>
__global__ __launch_bounds__(512, 1)
void wkv6_chunk(const unsigned short* __restrict__ r, const unsigned short* __restrict__ k16,
                const float* __restrict__ k32, const unsigned short* __restrict__ v,
                const float* __restrict__ dec, const float* __restrict__ u,
                unsigned short* __restrict__ gz,
                const float* __restrict__ lnw, const float* __restrict__ lnb) {
  __shared__ unsigned short Rh[4096], Rl[4096];     // R~ [t][i]
  __shared__ unsigned short Kh[4096], Kl[4096];     // K~ [s][i]
  __shared__ unsigned short KTh[4096], KTl[4096];   // K~^T [i][s]
  __shared__ unsigned short VTh[4096], VTl[4096];   // V^T [j][s]
  __shared__ unsigned short Amh[4096], Aml[4096];   // masked A [t][s]
  __shared__ unsigned short SThi[4096], STlo[4096]; // S^T bf16 hi/lo [j][i] (persistent)
  __shared__ float qpart[8][64];
  __shared__ float LcEnd[64];
  __shared__ float diagv[64];
  __shared__ float gnp[8][16][2];                   // per-wave GN partials

  const int bh = blockIdx.x, b = bh >> 5, h = bh & 31;
  const int tid = threadIdx.x;
  const int w = tid >> 6, lane = tid & 63;
  const int quad = lane >> 4, l15 = lane & 15;
  const int cb = h * 64;
  const int wr = w >> 1, wc = w & 1;
  const int rq = w * 8;            // operand-build row base (8 rows)
  const int mrow = wr * 16;        // MFMA C row base
  const int mcol = wc * 32;        // MFMA C col base

  const float uu = u[cb + lane];
  float lnwv[2], lnbv[2];
#pragma unroll
  for (int ni = 0; ni < 2; ++ni) {
    lnwv[ni] = lnw[cb + mcol + ni * 16 + l15];
    lnbv[ni] = lnb[cb + mcol + ni * 16 + l15];
  }

  for (int i = tid; i < 4096; i += 512) { SThi[i] = 0; STlo[i] = 0; }

  const size_t bT = (size_t)b * T_;

  // preload chunk 0 inputs (8 rows x {dec,r,k,v} per lane)
  float dA[8], rA[8], kA[8], vA[8];
  {
    const size_t ro = (bT + rq) * (size_t)A_ + cb + lane;
#pragma unroll
    for (int q = 0; q < 8; ++q) {
      const size_t o = ro + (size_t)q * A_;
      dA[q] = dec[o];
      rA[q] = bf2f(r[o]);
      if (KF32) kA[q] = k32[o];
      else      kA[q] = bf2f(k16[o]);
      vA[q] = h2f(v[o]);
    }
  }

  for (int c = 0; c < T_ / 64; ++c) {
    const int t0 = c * 64;
    // ---------- phase 1a: local cumprod over this wave's 8 rows ----------
    float lcq[8];
    lcq[0] = dA[0];
#pragma unroll
    for (int q = 1; q < 8; ++q) lcq[q] = lcq[q - 1] * dA[q];
    qpart[w][lane] = lcq[7];
    __syncthreads();                                  // B1 (orders ST init/update + qpart)
    // ---------- phase 1b: build operand tiles ----------
    {
      float pre = 1.f;
#pragma unroll
      for (int pw = 0; pw < 7; ++pw)
        if (pw < w) pre *= qpart[pw][lane];
      if (w == 7) LcEnd[lane] = pre * lcq[7];
      unsigned short hh, ll;
      // R/K rows + batched KT/VT values + diag
      short8 ktph, ktpl, vtph, vtpl;
#pragma unroll
      for (int q = 0; q < 8; ++q) {
        const int tr = rq + q;
        const float Pl = q ? pre * lcq[q - 1] : pre;
        const float Lc = pre * lcq[q];
        const int ix = swz(tr, lane);
        split_hl(rA[q] * Pl, hh, ll);
        Rh[ix] = hh; Rl[ix] = ll;
        const float kn = kA[q] / Lc;
        split_hl(kn, hh, ll);
        Kh[ix] = hh; Kl[ix] = ll;
        ktph[q] = (short)hh; ktpl[q] = (short)ll;
        split_hl(vA[q], hh, ll);
        vtph[q] = (short)hh; vtpl[q] = (short)ll;
        float dp = rA[q] * uu * kA[q];
        dp += __shfl_xor(dp, 1, 64);
        dp += __shfl_xor(dp, 2, 64);
        dp += __shfl_xor(dp, 4, 64);
        dp += __shfl_xor(dp, 8, 64);
        dp += __shfl_xor(dp, 16, 64);
        dp += __shfl_xor(dp, 32, 64);
        if (lane == 0) diagv[tr] = dp;
      }
      // transposed tiles: row = lane, cols rq..rq+7 (8-aligned, swizzle keeps 16B contiguity)
      const int ixT = lane * 64 + (rq ^ ((lane & 7) << 3));
      *(short8*)&KTh[ixT] = ktph;
      *(short8*)&KTl[ixT] = ktpl;
      *(short8*)&VTh[ixT] = vtph;
      *(short8*)&VTl[ixT] = vtpl;
    }
    __syncthreads();                                  // B2: tiles ready
    // ---------- prefetch next chunk inputs (overwrites dA..vA; last use was 1b) ----------
    if (c + 1 < T_ / 64) {
      const size_t ro = (bT + t0 + 64 + rq) * (size_t)A_ + cb + lane;
#pragma unroll
      for (int q = 0; q < 8; ++q) {
        const size_t o = ro + (size_t)q * A_;
        dA[q] = dec[o];
        rA[q] = bf2f(r[o]);
        if (KF32) kA[q] = k32[o];
        else      kA[q] = bf2f(k16[o]);
        vA[q] = h2f(v[o]);
      }
    }
    // ---------- merged phase 2+4a: A = R~ K~^T  AND  a4 = V^T K~ (held in regs) ----------
    floatx4 a4[2];
    {
      short8 arh[2], arl[2], avh[2], avl[2];
#pragma unroll
      for (int kst = 0; kst < 2; ++kst) {
        const int c8 = kst * 32 + quad * 8;
        arh[kst] = ldfrag(Rh, mrow + l15, c8);
        arl[kst] = ldfrag(Rl, mrow + l15, c8);
        avh[kst] = ldfrag(VTh, mrow + l15, c8);
        avl[kst] = ldfrag(VTl, mrow + l15, c8);
      }
      floatx4 accA[2];
#pragma unroll
      for (int ni = 0; ni < 2; ++ni) {
        floatx4 z = {0.f, 0.f, 0.f, 0.f};
        accA[ni] = z; a4[ni] = z;
      }
#pragma unroll
      for (int ni = 0; ni < 2; ++ni)
#pragma unroll
        for (int kst = 0; kst < 2; ++kst) {
          const int c8 = kst * 32 + quad * 8;
          short8 bh_ = ldfrag(Kh, mcol + ni * 16 + l15, c8);
          short8 bl_ = ldfrag(Kl, mcol + ni * 16 + l15, c8);
          accA[ni] = __builtin_amdgcn_mfma_f32_16x16x32_bf16(arh[kst], bh_, accA[ni], 0, 0, 0);
          accA[ni] = __builtin_amdgcn_mfma_f32_16x16x32_bf16(arh[kst], bl_, accA[ni], 0, 0, 0);
          accA[ni] = __builtin_amdgcn_mfma_f32_16x16x32_bf16(arl[kst], bh_, accA[ni], 0, 0, 0);
          short8 bkh = ldfrag(KTh, mcol + ni * 16 + l15, c8);
          short8 bkl = ldfrag(KTl, mcol + ni * 16 + l15, c8);
          a4[ni] = __builtin_amdgcn_mfma_f32_16x16x32_bf16(avh[kst], bkh, a4[ni], 0, 0, 0);
          a4[ni] = __builtin_amdgcn_mfma_f32_16x16x32_bf16(avh[kst], bkl, a4[ni], 0, 0, 0);
          a4[ni] = __builtin_amdgcn_mfma_f32_16x16x32_bf16(avl[kst], bkh, a4[ni], 0, 0, 0);
        }
      // A mask + store
#pragma unroll
      for (int ni = 0; ni < 2; ++ni)
#pragma unroll
        for (int vv = 0; vv < 4; ++vv) {
          const int grow = mrow + quad * 4 + vv;
          const int gcol = mcol + ni * 16 + l15;
          float val = (grow > gcol) ? accA[ni][vv] : ((grow == gcol) ? diagv[grow] : 0.f);
          unsigned short hh, ll;
          split_hl(val, hh, ll);
          const int ix = swz(grow, gcol);
          Amh[ix] = hh; Aml[ix] = ll;
        }
    }
    __syncthreads();                                  // B3: Am ready (prefetch drains here)
    // ---------- phase 3: Y = A V + R~ S0 (OLD S), GN*g epilogue ----------
    {
      // g prefetch: thread-private offsets (same thread writes back after B4)
      unsigned short gv[2][4];
#pragma unroll
      for (int ni = 0; ni < 2; ++ni)
#pragma unroll
        for (int vv = 0; vv < 4; ++vv) {
          const size_t off = (bT + t0 + mrow + quad * 4 + vv) * (size_t)A_ + cb + mcol + ni * 16 + l15;
          gv[ni][vv] = gz[off];
        }
      short8 aAh[2], aAl[2], aRh[2], aRl[2];
#pragma unroll
      for (int kst = 0; kst < 2; ++kst) {
        const int c8 = kst * 32 + quad * 8;
        aAh[kst] = ldfrag(Amh, mrow + l15, c8);
        aAl[kst] = ldfrag(Aml, mrow + l15, c8);
        aRh[kst] = ldfrag(Rh, mrow + l15, c8);
        aRl[kst] = ldfrag(Rl, mrow + l15, c8);
      }
      floatx4 acc[2];
#pragma unroll
      for (int ni = 0; ni < 2; ++ni) { floatx4 z = {0.f, 0.f, 0.f, 0.f}; acc[ni] = z; }
#pragma unroll
      for (int ni = 0; ni < 2; ++ni)
#pragma unroll
        for (int kst = 0; kst < 2; ++kst) {
          const int c8 = kst * 32 + quad * 8;
          const int brow = mcol + ni * 16 + l15;
          short8 bvh = ldfrag(VTh, brow, c8);
          short8 bvl = ldfrag(VTl, brow, c8);
          acc[ni] = __builtin_amdgcn_mfma_f32_16x16x32_bf16(aAh[kst], bvh, acc[ni], 0, 0, 0);
          acc[ni] = __builtin_amdgcn_mfma_f32_16x16x32_bf16(aAh[kst], bvl, acc[ni], 0, 0, 0);
          acc[ni] = __builtin_amdgcn_mfma_f32_16x16x32_bf16(aAl[kst], bvh, acc[ni], 0, 0, 0);
          short8 bsh = ldfrag(SThi, brow, c8);
          short8 bsl = ldfrag(STlo, brow, c8);
          acc[ni] = __builtin_amdgcn_mfma_f32_16x16x32_bf16(aRh[kst], bsh, acc[ni], 0, 0, 0);
          acc[ni] = __builtin_amdgcn_mfma_f32_16x16x32_bf16(aRh[kst], bsl, acc[ni], 0, 0, 0);
          acc[ni] = __builtin_amdgcn_mfma_f32_16x16x32_bf16(aRl[kst], bsh, acc[ni], 0, 0, 0);
        }
      // GN partials over this wave's 32 cols; exchange with partner wave (w^1)
      float s1_[4], s2_[4];
#pragma unroll
      for (int vv = 0; vv < 4; ++vv) {
        float s1 = acc[0][vv] + acc[1][vv];
        float s2 = acc[0][vv] * acc[0][vv] + acc[1][vv] * acc[1][vv];
        s1 += __shfl_xor(s1, 1, 64); s2 += __shfl_xor(s2, 1, 64);
        s1 += __shfl_xor(s1, 2, 64); s2 += __shfl_xor(s2, 2, 64);
        s1 += __shfl_xor(s1, 4, 64); s2 += __shfl_xor(s2, 4, 64);
        s1 += __shfl_xor(s1, 8, 64); s2 += __shfl_xor(s2, 8, 64);
        s1_[vv] = s1; s2_[vv] = s2;
        if (l15 == 0) {
          gnp[w][quad * 4 + vv][0] = s1;
          gnp[w][quad * 4 + vv][1] = s2;
        }
      }
      __syncthreads();                                // B4: GN partials ready; all pair reads drained
#pragma unroll
      for (int ni = 0; ni < 2; ++ni)
#pragma unroll
        for (int vv = 0; vv < 4; ++vv) {
          const int rloc = quad * 4 + vv;
          float s1 = s1_[vv] + gnp[w ^ 1][rloc][0];
          float s2 = s2_[vv] + gnp[w ^ 1][rloc][1];
          float mu = s1 * (1.f / 64.f);
          float var = s2 * (1.f / 64.f) - mu * mu;
          float rs = rsqrtf(var + 6.4e-4f);           // EPS = 1e-5 * 64
          const size_t off = (bT + t0 + mrow + rloc) * (size_t)A_ + cb + mcol + ni * 16 + l15;
          float yn = (acc[ni][vv] - mu) * rs * lnwv[ni] + lnbv[ni];
          float z = yn * h2f(gv[ni][vv]);
          gz[off] = f2h(z);
        }
    }
    // ---------- phase 4b (post-B4): S = LcEnd .* (a4 + S_old), per-wave disjoint ----------
    {
#pragma unroll
      for (int ni = 0; ni < 2; ++ni) {
        const float lce = LcEnd[mcol + ni * 16 + l15];
#pragma unroll
        for (int vv = 0; vv < 4; ++vv) {
          const int jr = mrow + quad * 4 + vv;
          const int ic = mcol + ni * 16 + l15;
          const int ix = swz(jr, ic);
          float sold = bf2f(SThi[ix]) + bf2f(STlo[ix]);
          float snew = lce * (a4[ni][vv] + sold);
          unsigned short hh, ll;
          split_hl(snew, hh, ll);
          SThi[ix] = hh; STlo[ix] = ll;
        }
      }
    }
    // no B5: pair writes ordered vs next reads by next B1/B2
  }
}

// ---------------- launch ----------------
extern "C" void kernel_launch(void* const* d_in, const int* in_sizes, int n_in,
                              void* d_out, int out_size, void* d_ws, size_t ws_size,
                              hipStream_t stream) {
  (void)in_sizes; (void)n_in; (void)out_size;
  const float* x   = (const float*)d_in[0];
  const float* tmx = (const float*)d_in[1];
  const float* tmw = (const float*)d_in[2];
  const float* tmk = (const float*)d_in[3];
  const float* tmv = (const float*)d_in[4];
  const float* tmr = (const float*)d_in[5];
  const float* tmg = (const float*)d_in[6];
  const float* w1  = (const float*)d_in[7];   // (C,160)
  const float* w2  = (const float*)d_in[8];   // (5,32,C)
  const float* td  = (const float*)d_in[9];   // (A)
  const float* dw1 = (const float*)d_in[10];  // (C,64)
  const float* dw2 = (const float*)d_in[11];  // (64,A)
  const float* u   = (const float*)d_in[12];  // (H,N)
  const float* Wr  = (const float*)d_in[13];
  const float* Wk  = (const float*)d_in[14];
  const float* Wv  = (const float*)d_in[15];
  const float* Wg  = (const float*)d_in[16];
  const float* Wo  = (const float*)d_in[17];
  const float* lnw = (const float*)d_in[18];
  const float* lnb = (const float*)d_in[19];

  char* ws = (char*)d_ws;
  const size_t MB = 1024 * 1024;
  // 472MB layout (proven safe footprint), lifetime-overlapped:
  // [0,64)    U0: xxx -> g (f16) -> z (f16, in place)
  // [64,72.4)     m5 (f16) -> vf (f16, 33.5MB, step 8+; m5 dead after step 3)
  // [128,192) U2: bxk (w1T scratch at [128,129) pre-mix)
  // [192,256) U3: bxv -> dec lower half
  // [256,320) U4: bxw -> dec upper half     (dec = [192,320) f32)
  // [320,384) U5: bxg -> r (bf16)
  // [384,448) U6: bxr -> k (bf16, L0)
  // [448,456.4)   Wf16 scratch (dw1T pre) -> Wf16 per projection
  // [460,460.7)   w2T (f16; read during mix_gemm only)
  // [464,472)     t1 (f32, 8MB)
  // x16 (67MB, f16 copy of x, live steps 1-3 only) lives in d_out (134MB,
  // fully overwritten at step 11) -> zero workspace cost, no overlap.
  unsigned short* xxx  = (unsigned short*)(ws + 0 * MB);
  unsigned short* gb   = (unsigned short*)(ws + 0 * MB);     // g then z (f16)
  unsigned short* m5   = (unsigned short*)(ws + 64 * MB);    // f16
  unsigned short* vf   = (unsigned short*)(ws + 64 * MB);    // v f16 (step 8+)
  unsigned short* w1T  = (unsigned short*)(ws + 128 * MB);
  unsigned short* bxk  = (unsigned short*)(ws + 128 * MB);
  unsigned short* bxv  = (unsigned short*)(ws + 192 * MB);
  float*          decb = (float*)(ws + 192 * MB);            // dec f32 [192,320)
  unsigned short* bxw  = (unsigned short*)(ws + 256 * MB);
  unsigned short* bxg  = (unsigned short*)(ws + 320 * MB);
  unsigned short* rb   = (unsigned short*)(ws + 320 * MB);   // r (bf16)
  unsigned short* bxr  = (unsigned short*)(ws + 384 * MB);
  unsigned short* kb   = (unsigned short*)(ws + 384 * MB);   // k bf16 (L0)
  unsigned short* dw1T = (unsigned short*)(ws + 448 * MB);
  unsigned short* Wf   = (unsigned short*)(ws + 448 * MB);   // f16 weight scratch
  unsigned short* w2T  = (unsigned short*)(ws + 460 * MB);   // (5,2048,32) f16
  float*          t1   = (float*)(ws + 464 * MB);
  unsigned short* x16  = (unsigned short*)d_out;             // f16 x copy in d_out scratch
  const bool kf32 = false;                                   // k stays bf16 (proven path)
  float* kf = (float*)(ws + 480 * MB);

  const int nW = A_ * C_;  // 4.19M elements
  const size_t EBT = (size_t)BT_ * C_;

  // 1. token-shift mix -> xxx (f16) + x16 (f16 copy, staged in d_out)
  shift_mix<<<(int)(EBT / 4 / 256), 256, 0, stream>>>(x, tmx, xxx, x16);

  // 2. m5 = tanh(xxx @ maa_w1) padded N=256 (f16 out)
  transpose_pad<<<(256 * 2048) / 256, 256, 0, stream>>>(w1, w1T, 256, 160);
  gemm_f16<4><<<dim3(BT_ / 128, 2), 256, 0, stream>>>(xxx, w1T, m5, BT_, 256, 2048);

  // 3. five mixed inputs via MFMA mix, f on blockIdx.z (needs w2T; coalesced epilogue)
  transpose_w2<<<(5 * 65536) / 256, 256, 0, stream>>>(w2, w2T);
  mix_gemm<<<dim3(BT_ / 128, C_ / 128, 5), 256, 0, stream>>>(m5, w2T, x16,
                                                             tmw, tmk, tmv, tmr, tmg,
                                                             bxw, bxk, bxv, bxr, bxg);

  // 4. t1 = tanh(xw @ decay_w1) padded N=128 (f32 out)
  transpose_pad<<<(128 * 2048) / 256, 256, 0, stream>>>(dw1, dw1T, 128, 64);
  gemm_f16<2><<<dim3(BT_ / 128, 1), 256, 0, stream>>>(bxw, dw1T, t1, BT_, 128, 2048);

  // 5-8. projections with f16 weights, 256^2 pipelined GEMM (v now f16 out)
  conv_f16<<<nW / 256, 256, 0, stream>>>(Wg, Wf, nW);
  gemm256<1><<<dim3(BT_ / 256, C_ / 256), 512, 0, stream>>>(bxg, Wf, gb, BT_, 2048, 2048);
  conv_f16<<<nW / 256, 256, 0, stream>>>(Wr, Wf, nW);
  gemm256<0><<<dim3(BT_ / 256, C_ / 256), 512, 0, stream>>>(bxr, Wf, rb, BT_, 2048, 2048);
  conv_f16<<<nW / 256, 256, 0, stream>>>(Wk, Wf, nW);
  gemm256<0><<<dim3(BT_ / 256, C_ / 256), 512, 0, stream>>>(bxk, Wf, kb, BT_, 2048, 2048);
  conv_f16<<<nW / 256, 256, 0, stream>>>(Wv, Wf, nW);
  gemm256<5><<<dim3(BT_ / 256, C_ / 256), 512, 0, stream>>>(bxv, Wf, vf, BT_, 2048, 2048);

  // 9. dec (after bxv/bxw are dead; overlays them)
  decay_kernel<<<BT_ / 16, 256, 0, stream>>>(t1, dw2, td, decb);

  // 10. WKV6 chunk-parallel MFMA (8 waves, 4 barriers/chunk) + fused GroupNorm*g
  wkv6_chunk<0><<<256, 512, 0, stream>>>(rb, kb, kf, vf, decb, u, gb, lnw, lnb);

  // 11. output projection: z @ Wo^T (both f16) -> d_out (f32, overwrites x16 scratch)
  conv_f16<<<nW / 256, 256, 0, stream>>>(Wo, Wf, nW);
  gemm256<3><<<dim3(BT_ / 256, C_ / 256), 512, 0, stream>>>(gb, Wf, (float*)d_out, BT_, 2048, 2048);
}

// Round 18
// 1809.795 us; speedup vs baseline: 1.0505x; 1.0505x over previous
//
#include <hip/hip_runtime.h>
#include <hip/hip_bf16.h>
#include <cstdint>
#include <cstddef>

#define B_ 8
#define T_ 2048
#define C_ 2048
#define A_ 2048
#define H_ 32
#define BT_ (B_*T_)

typedef short short8 __attribute__((ext_vector_type(8)));
typedef _Float16 half8 __attribute__((ext_vector_type(8)));
typedef float floatx4 __attribute__((ext_vector_type(4)));

__device__ __forceinline__ unsigned short f2bf(float f) {
  union { float f; uint32_t u; } a; a.f = f;
  uint32_t r = a.u + 0x7fffu + ((a.u >> 16) & 1u);   // RNE
  return (unsigned short)(r >> 16);
}
__device__ __forceinline__ float bf2f(unsigned short s) {
  union { uint32_t u; float f; } a; a.u = ((uint32_t)s) << 16;
  return a.f;
}
__device__ __forceinline__ unsigned short f2h(float f) {
  union { _Float16 h; unsigned short u; } c; c.h = (_Float16)f; return c.u;
}
__device__ __forceinline__ float h2f(unsigned short u) {
  union { unsigned short u; _Float16 h; } c; c.u = u; return (float)c.h;
}
__device__ __forceinline__ void split_hl(float v, unsigned short& hh, unsigned short& ll) {
  hh = f2bf(v);
  ll = f2bf(v - bf2f(hh));
}
// XOR-swizzled index into a row-major [64][64] bf16 LDS tile (G4 recipe)
__device__ __forceinline__ int swz(int row, int col) {
  return row * 64 + (col ^ ((row & 7) << 3));
}
__device__ __forceinline__ short8 ldfrag(const unsigned short* M, int row, int col8) {
  return *(const short8*)&M[row * 64 + (col8 ^ ((row & 7) << 3))];
}

// ---------------- weight prep: f32 -> f16 ----------------
__global__ void conv_f16(const float* __restrict__ s, unsigned short* __restrict__ d, int n) {
  int i = blockIdx.x * 256 + threadIdx.x;
  if (i < n) d[i] = f2h(s[i]);
}

// src (2048 x NV) f32 -> dst (NP x 2048) f16, rows >= NV zero-padded
__global__ void transpose_pad(const float* __restrict__ s, unsigned short* __restrict__ d, int NP, int NV) {
  int i = blockIdx.x * 256 + threadIdx.x;  // over NP*2048
  int n = i >> 11, kk = i & 2047;
  if (n < NP) d[i] = (n < NV) ? f2h(s[kk * NV + n]) : (unsigned short)0;
}

// w2 (5,32,C) f32 -> w2T (5,C,32) f16 (read-coalesced; scattered writes L2-absorbed)
__global__ void transpose_w2(const float* __restrict__ s, unsigned short* __restrict__ d) {
  int i = blockIdx.x * 256 + threadIdx.x;   // over 5*32*2048
  int f = i >> 16, rem = i & 65535;
  int dd = rem >> 11, c = rem & 2047;
  d[((size_t)(f * 2048 + c) << 5) + dd] = f2h(s[((size_t)(f * 32 + dd) << 11) + c]);
}

// ---------------- token shift + maa_x mix (f16 out) + f16 copy of x ----------------
__global__ void shift_mix(const float* __restrict__ x, const float* __restrict__ tmx,
                          unsigned short* __restrict__ xxx, unsigned short* __restrict__ x16) {
  size_t i4 = (size_t)blockIdx.x * 256 + threadIdx.x;   // over BT*C/4
  size_t i = i4 * 4;
  int c = (int)(i & 2047);
  int t = (int)((i >> 11) & 2047);
  float4 xv = *(const float4*)&x[i];
  float4 pv = make_float4(0.f, 0.f, 0.f, 0.f);
  if (t > 0) pv = *(const float4*)&x[i - 2048];
  float4 tv = *(const float4*)&tmx[c];
  ushort4 m;
  m.x = f2h(xv.x + (pv.x - xv.x) * tv.x);
  m.y = f2h(xv.y + (pv.y - xv.y) * tv.y);
  m.z = f2h(xv.z + (pv.z - xv.z) * tv.z);
  m.w = f2h(xv.w + (pv.w - xv.w) * tv.w);
  *(ushort4*)&xxx[i] = m;
  ushort4 xh;
  xh.x = f2h(xv.x); xh.y = f2h(xv.y); xh.z = f2h(xv.z); xh.w = f2h(xv.w);
  *(ushort4*)&x16[i] = xh;
}

// ---------------- async global->LDS helper ----------------
__device__ __forceinline__ void gll16(const void* g, void* l) {
  __builtin_amdgcn_global_load_lds(
      (const __attribute__((address_space(1))) void*)g,
      (__attribute__((address_space(3))) void*)l, 16, 0, 0);
}

// ---------------- f16 GEMM, 128^2 tile (small-N lora paths): C = A * B^T ----------------
// EPI: 0 = ->bf16, 1 = silu->f16, 2 = tanh->f32, 3 = ->f32, 4 = tanh->f16
template<int EPI>
__global__ __launch_bounds__(256)
void gemm_f16(const unsigned short* __restrict__ Am, const unsigned short* __restrict__ Bm,
              void* __restrict__ Cp, int M, int N, int K) {
  __shared__ unsigned short As[128 * 32];
  __shared__ unsigned short Bs[128 * 32];
  const int tid = threadIdx.x;
  const int wid = tid >> 6, lane = tid & 63;
  const int quad = lane >> 4, l15 = lane & 15;
  const long bm = (long)blockIdx.x * 128, bn = (long)blockIdx.y * 128;
  const int wm = (wid & 1) * 64, wn = (wid >> 1) * 64;

  floatx4 acc[4][4];
#pragma unroll
  for (int a = 0; a < 4; a++)
#pragma unroll
    for (int b = 0; b < 4; b++) { floatx4 z = {0.f, 0.f, 0.f, 0.f}; acc[a][b] = z; }

  const int stg_row = wid * 32 + (lane >> 2);
  const int stg_k   = (lane & 3) * 8;
  const int stg_lds = wid * 1024 + lane * 8;

  for (int k0 = 0; k0 < K; k0 += 32) {
    __syncthreads();
#pragma unroll
    for (int p = 0; p < 2; ++p) {
      gll16(Am + (bm + stg_row + p * 16) * (long)K + k0 + stg_k, &As[stg_lds + p * 512]);
      gll16(Bm + (bn + stg_row + p * 16) * (long)K + k0 + stg_k, &Bs[stg_lds + p * 512]);
    }
    __syncthreads();

    half8 af[4], bfr[4];
#pragma unroll
    for (int mi = 0; mi < 4; mi++) af[mi] = *(const half8*)&As[(wm + mi * 16 + l15) * 32 + quad * 8];
#pragma unroll
    for (int ni = 0; ni < 4; ni++) bfr[ni] = *(const half8*)&Bs[(wn + ni * 16 + l15) * 32 + quad * 8];
#pragma unroll
    for (int mi = 0; mi < 4; mi++)
#pragma unroll
      for (int ni = 0; ni < 4; ni++)
        acc[mi][ni] = __builtin_amdgcn_mfma_f32_16x16x32_f16(af[mi], bfr[ni], acc[mi][ni], 0, 0, 0);
  }

#pragma unroll
  for (int mi = 0; mi < 4; mi++)
#pragma unroll
    for (int ni = 0; ni < 4; ni++)
#pragma unroll
      for (int vv = 0; vv < 4; ++vv) {
        long row = bm + wm + mi * 16 + quad * 4 + vv;
        long col = bn + wn + ni * 16 + l15;
        float val = acc[mi][ni][vv];
        if (EPI == 0) {
          ((unsigned short*)Cp)[row * N + col] = f2bf(val);
        } else if (EPI == 1) {
          float s = val / (1.f + __expf(-val));
          ((unsigned short*)Cp)[row * N + col] = f2h(s);
        } else if (EPI == 2) {
          ((float*)Cp)[row * N + col] = tanhf(val);
        } else if (EPI == 4) {
          ((unsigned short*)Cp)[row * N + col] = f2h(tanhf(val));
        } else {
          ((float*)Cp)[row * N + col] = val;
        }
      }
}

// ---------------- f16 GEMM, 256^2 tile, BK=32, 4-buffer counted-vmcnt pipeline ----------------
// v15 swizzle: key ((r>>1)&3) -> conflict-free frag reads (2-way = free, m136)
template<int EPI>
__global__ __launch_bounds__(512, 2)
void gemm256(const unsigned short* __restrict__ Am, const unsigned short* __restrict__ Bm,
             void* __restrict__ Cp, int M, int N, int K) {
  __shared__ unsigned short At[4][8192];
  __shared__ unsigned short Bt[4][8192];
  const int tid = threadIdx.x;
  const int w = tid >> 6, lane = tid & 63;
  const int quad = lane >> 4, l15 = lane & 15;
  const long bm = (long)blockIdx.x * 256, bn = (long)blockIdx.y * 256;
  const int wm = (w & 1) * 128, wn = (w >> 1) * 64;

  floatx4 acc[8][4];
#pragma unroll
  for (int a = 0; a < 8; a++)
#pragma unroll
    for (int b = 0; b < 4; b++) { floatx4 z = {0.f, 0.f, 0.f, 0.f}; acc[a][b] = z; }

  int srow[2], scol[2];
#pragma unroll
  for (int u = 0; u < 2; ++u) {
    int p = u * 8192 + tid * 16;
    int l = p ^ (((p >> 7) & 3) << 4);
    srow[u] = l >> 6;
    scol[u] = (l & 63) >> 1;
  }
  const int ldst = tid * 16;   // byte offset of this thread's 16B within a unit

  const int NT = K >> 5;
  for (int t = 0; t < 3; ++t) {
#pragma unroll
    for (int u = 0; u < 2; ++u) {
      gll16(Am + (bm + srow[u]) * (long)K + (t << 5) + scol[u],
            (char*)&At[t][0] + u * 8192 + ldst);
      gll16(Bm + (bn + srow[u]) * (long)K + (t << 5) + scol[u],
            (char*)&Bt[t][0] + u * 8192 + ldst);
    }
  }
  asm volatile("s_waitcnt vmcnt(8) lgkmcnt(0)\n\ts_barrier" ::: "memory");

  for (int t = 0; t < NT; ++t) {
    const int bi = t & 3;
    const unsigned short* Ab = At[bi];
    const unsigned short* Bb = Bt[bi];
    const int tn = t + 3;
    const bool do_stage = tn < NT;
    const int bj = tn & 3;

    if (do_stage) {
      gll16(Am + (bm + srow[0]) * (long)K + (tn << 5) + scol[0], (char*)&At[bj][0] + ldst);
      gll16(Bm + (bn + srow[0]) * (long)K + (tn << 5) + scol[0], (char*)&Bt[bj][0] + ldst);
    }
    half8 bfr[4], af[4];
#pragma unroll
    for (int ni = 0; ni < 4; ++ni) {
      int r = wn + ni * 16 + l15;
      bfr[ni] = *(const half8*)((const char*)Bb + r * 64 + ((quad ^ ((r >> 1) & 3)) << 4));
    }
#pragma unroll
    for (int mi = 0; mi < 4; ++mi) {
      int r = wm + mi * 16 + l15;
      af[mi] = *(const half8*)((const char*)Ab + r * 64 + ((quad ^ ((r >> 1) & 3)) << 4));
    }
    __builtin_amdgcn_s_setprio(1);
#pragma unroll
    for (int mi = 0; mi < 4; ++mi)
#pragma unroll
      for (int ni = 0; ni < 4; ++ni)
        acc[mi][ni] = __builtin_amdgcn_mfma_f32_16x16x32_f16(af[mi], bfr[ni], acc[mi][ni], 0, 0, 0);
    __builtin_amdgcn_s_setprio(0);

    if (do_stage) {
      gll16(Am + (bm + srow[1]) * (long)K + (tn << 5) + scol[1], (char*)&At[bj][0] + 8192 + ldst);
      gll16(Bm + (bn + srow[1]) * (long)K + (tn << 5) + scol[1], (char*)&Bt[bj][0] + 8192 + ldst);
    }
#pragma unroll
    for (int mi = 0; mi < 4; ++mi) {
      int r = wm + 64 + mi * 16 + l15;
      af[mi] = *(const half8*)((const char*)Ab + r * 64 + ((quad ^ ((r >> 1) & 3)) << 4));
    }
    __builtin_amdgcn_s_setprio(1);
#pragma unroll
    for (int mi = 0; mi < 4; ++mi)
#pragma unroll
      for (int ni = 0; ni < 4; ++ni)
        acc[4 + mi][ni] = __builtin_amdgcn_mfma_f32_16x16x32_f16(af[mi], bfr[ni], acc[4 + mi][ni], 0, 0, 0);
    __builtin_amdgcn_s_setprio(0);

    asm volatile("s_waitcnt vmcnt(8) lgkmcnt(0)\n\ts_barrier" ::: "memory");
  }

#pragma unroll
  for (int p = 0; p < 2; ++p)
#pragma unroll
    for (int mi = 0; mi < 4; ++mi)
#pragma unroll
      for (int ni = 0; ni < 4; ++ni)
#pragma unroll
        for (int vv = 0; vv < 4; ++vv) {
          long row = bm + wm + p * 64 + mi * 16 + quad * 4 + vv;
          long col = bn + wn + ni * 16 + l15;
          float val = acc[p * 4 + mi][ni][vv];
          if (EPI == 0) {
            ((unsigned short*)Cp)[row * N + col] = f2bf(val);
          } else if (EPI == 1) {
            float s = val / (1.f + __expf(-val));
            ((unsigned short*)Cp)[row * N + col] = f2h(s);
          } else {
            ((float*)Cp)[row * N + col] = val;
          }
        }
}

// ---------------- MFMA LoRA-mix, f on blockIdx.z; fully-coalesced epilogue ----------------
// v16 (proven): delta staged to LDS zs[128][136]; write-out re-tiled to short8
// full-line streams (no RMW, no read amplification).
__global__ __launch_bounds__(256)
void mix_gemm(const unsigned short* __restrict__ m5f, const unsigned short* __restrict__ w2T,
              const unsigned short* __restrict__ x16,
              const float* __restrict__ tmw, const float* __restrict__ tmk,
              const float* __restrict__ tmv, const float* __restrict__ tmr,
              const float* __restrict__ tmg,
              unsigned short* __restrict__ xw, unsigned short* __restrict__ xk,
              unsigned short* __restrict__ xv, unsigned short* __restrict__ xr,
              unsigned short* __restrict__ xg) {
  __shared__ unsigned short As[128 * 32];
  __shared__ unsigned short Bs[128 * 32];
  __shared__ unsigned short zs[128 * 136];   // padded lora-delta tile (f16)
  const int tid = threadIdx.x;
  const int wid = tid >> 6, lane = tid & 63;
  const int quad = lane >> 4, l15 = lane & 15;
  const long bm = (long)blockIdx.x * 128, bn = (long)blockIdx.y * 128;
  const int f = blockIdx.z;
  const int wm = (wid & 1) * 64, wn = (wid >> 1) * 64;

  const float* tmf = (f == 0) ? tmw : (f == 1) ? tmk : (f == 2) ? tmv : (f == 3) ? tmr : tmg;
  unsigned short* outf = (f == 0) ? xw : (f == 1) ? xk : (f == 2) ? xv : (f == 3) ? xr : xg;

  const int stg_row = wid * 32 + (lane >> 2);
  const int stg_k   = (lane & 3) * 8;
  const int stg_lds = wid * 1024 + lane * 8;

#pragma unroll
  for (int p = 0; p < 2; ++p) {
    gll16(m5f + (bm + stg_row + p * 16) * 256 + f * 32 + stg_k, &As[stg_lds + p * 512]);
    gll16(w2T + ((long)f * 2048 + bn + stg_row + p * 16) * 32 + stg_k, &Bs[stg_lds + p * 512]);
  }
  __syncthreads();

  half8 af[4], bfr[4];
#pragma unroll
  for (int mi = 0; mi < 4; mi++) af[mi] = *(const half8*)&As[(wm + mi * 16 + l15) * 32 + quad * 8];
#pragma unroll
  for (int ni = 0; ni < 4; ni++) bfr[ni] = *(const half8*)&Bs[(wn + ni * 16 + l15) * 32 + quad * 8];

  floatx4 acc[4][4];
#pragma unroll
  for (int a = 0; a < 4; a++)
#pragma unroll
    for (int b = 0; b < 4; b++) { floatx4 z = {0.f, 0.f, 0.f, 0.f}; acc[a][b] = z; }
#pragma unroll
  for (int mi = 0; mi < 4; mi++)
#pragma unroll
    for (int ni = 0; ni < 4; ni++)
      acc[mi][ni] = __builtin_amdgcn_mfma_f32_16x16x32_f16(af[mi], bfr[ni], acc[mi][ni], 0, 0, 0);

  // stage delta to LDS
#pragma unroll
  for (int mi = 0; mi < 4; mi++)
#pragma unroll
    for (int ni = 0; ni < 4; ni++)
#pragma unroll
      for (int vv = 0; vv < 4; ++vv)
        zs[(wm + mi * 16 + quad * 4 + vv) * 136 + wn + ni * 16 + l15] = f2h(acc[mi][ni][vv]);
  __syncthreads();

  // write-out: thread -> (row = pass*16 + tid>>4, cols (tid&15)*8 .. +8)
#pragma unroll
  for (int pass = 0; pass < 8; ++pass) {
    const int row = pass * 16 + (tid >> 4);
    const int c8 = (tid & 15) * 8;
    const long grow = bm + row;
    const size_t gidx = (size_t)grow * 2048 + bn + c8;
    short8 xv8 = *(const short8*)&x16[gidx];
    short8 xp8;
    if ((grow & 2047) > 0) xp8 = *(const short8*)&x16[gidx - 2048];
    else { short8 zz = {0, 0, 0, 0, 0, 0, 0, 0}; xp8 = zz; }
    short8 d8 = *(const short8*)&zs[row * 136 + c8];
    short8 o8;
#pragma unroll
    for (int j = 0; j < 8; ++j) {
      float xc = h2f((unsigned short)xv8[j]);
      float xp = ((grow & 2047) > 0) ? h2f((unsigned short)xp8[j]) : 0.f;
      float tv = tmf[bn + c8 + j];
      o8[j] = (short)f2h(xc + (xp - xc) * (tv + h2f((unsigned short)d8[j])));
    }
    *(short8*)&outf[gidx] = o8;
  }
}

// ---------------- decay: dec = exp(-exp(td + t1 @ decay_w2)) (f32) ----------------
__global__ __launch_bounds__(256)
void decay_kernel(const float* __restrict__ t1, const float* __restrict__ w2d,
                  const float* __restrict__ td, float* __restrict__ dec) {
  const int bt0 = blockIdx.x * 16;
  const int tid = threadIdx.x;
  for (int cc = 0; cc < 8; ++cc) {
    const int a = cc * 256 + tid;
    const float tda = td[a];
    float acc[16];
#pragma unroll
    for (int b = 0; b < 16; b++) acc[b] = 0.f;
    for (int dc = 0; dc < 16; ++dc) {
      float wv0 = w2d[((size_t)(dc * 4 + 0) << 11) + a];
      float wv1 = w2d[((size_t)(dc * 4 + 1) << 11) + a];
      float wv2 = w2d[((size_t)(dc * 4 + 2) << 11) + a];
      float wv3 = w2d[((size_t)(dc * 4 + 3) << 11) + a];
#pragma unroll
      for (int b = 0; b < 16; b++) {
        float4 mv = *(const float4*)&t1[((size_t)(bt0 + b) << 7) + dc * 4];
        acc[b] += mv.x * wv0 + mv.y * wv1 + mv.z * wv2 + mv.w * wv3;
      }
    }
#pragma unroll
    for (int b = 0; b < 16; b++) {
      dec[((size_t)(bt0 + b) << 11) + a] = __expf(-__expf(tda + acc[b]));
    }
  }
}

// ---------------- WKV6 chunk-parallel (MFMA) + fused GroupNorm*g, 8 waves ----------------
// v16 structure (proven 262us, reverted from v17/v18 regressions): 4 barriers/
// chunk; S as bf16 hi/lo pair only; S-update deferred post-B4; merged phase
// 2+4a; g prefetch after B3; v read as f32 (conversion-free prefetch loads —
// v18 showed h2f at the load site exposes prefetch latency).
// v19: + s_setprio(1) around both MFMA clusters (T5: pays in phase-split
// multi-wave schedules; scheduler hint only, zero correctness risk).
template<int KF32>
__global__ __launch_bounds__(512, 1)
void wkv6_chunk(const unsigned short* __restrict__ r, const unsigned short* __restrict__ k16,
                const float* __restrict__ k32, const float* __restrict__ v,
                const float* __restrict__ dec, const float* __restrict__ u,
                unsigned short* __restrict__ gz,
                const float* __restrict__ lnw, const float* __restrict__ lnb) {
  __shared__ unsigned short Rh[4096], Rl[4096];     // R~ [t][i]
  __shared__ unsigned short Kh[4096], Kl[4096];     // K~ [s][i]
  __shared__ unsigned short KTh[4096], KTl[4096];   // K~^T [i][s]
  __shared__ unsigned short VTh[4096], VTl[4096];   // V^T [j][s]
  __shared__ unsigned short Amh[4096], Aml[4096];   // masked A [t][s]
  __shared__ unsigned short SThi[4096], STlo[4096]; // S^T bf16 hi/lo [j][i] (persistent)
  __shared__ float qpart[8][64];
  __shared__ float LcEnd[64];
  __shared__ float diagv[64];
  __shared__ float gnp[8][16][2];                   // per-wave GN partials

  const int bh = blockIdx.x, b = bh >> 5, h = bh & 31;
  const int tid = threadIdx.x;
  const int w = tid >> 6, lane = tid & 63;
  const int quad = lane >> 4, l15 = lane & 15;
  const int cb = h * 64;
  const int wr = w >> 1, wc = w & 1;
  const int rq = w * 8;            // operand-build row base (8 rows)
  const int mrow = wr * 16;        // MFMA C row base
  const int mcol = wc * 32;        // MFMA C col base

  const float uu = u[cb + lane];
  float lnwv[2], lnbv[2];
#pragma unroll
  for (int ni = 0; ni < 2; ++ni) {
    lnwv[ni] = lnw[cb + mcol + ni * 16 + l15];
    lnbv[ni] = lnb[cb + mcol + ni * 16 + l15];
  }

  for (int i = tid; i < 4096; i += 512) { SThi[i] = 0; STlo[i] = 0; }

  const size_t bT = (size_t)b * T_;

  // preload chunk 0 inputs (8 rows x {dec,r,k,v} per lane)
  float dA[8], rA[8], kA[8], vA[8];
  {
    const size_t ro = (bT + rq) * (size_t)A_ + cb + lane;
#pragma unroll
    for (int q = 0; q < 8; ++q) {
      const size_t o = ro + (size_t)q * A_;
      dA[q] = dec[o];
      rA[q] = bf2f(r[o]);
      if (KF32) kA[q] = k32[o];
      else      kA[q] = bf2f(k16[o]);
      vA[q] = v[o];
    }
  }

  for (int c = 0; c < T_ / 64; ++c) {
    const int t0 = c * 64;
    // ---------- phase 1a: local cumprod over this wave's 8 rows ----------
    float lcq[8];
    lcq[0] = dA[0];
#pragma unroll
    for (int q = 1; q < 8; ++q) lcq[q] = lcq[q - 1] * dA[q];
    qpart[w][lane] = lcq[7];
    __syncthreads();                                  // B1 (orders ST init/update + qpart)
    // ---------- phase 1b: build operand tiles ----------
    {
      float pre = 1.f;
#pragma unroll
      for (int pw = 0; pw < 7; ++pw)
        if (pw < w) pre *= qpart[pw][lane];
      if (w == 7) LcEnd[lane] = pre * lcq[7];
      unsigned short hh, ll;
      // R/K rows + batched KT/VT values + diag
      short8 ktph, ktpl, vtph, vtpl;
#pragma unroll
      for (int q = 0; q < 8; ++q) {
        const int tr = rq + q;
        const float Pl = q ? pre * lcq[q - 1] : pre;
        const float Lc = pre * lcq[q];
        const int ix = swz(tr, lane);
        split_hl(rA[q] * Pl, hh, ll);
        Rh[ix] = hh; Rl[ix] = ll;
        const float kn = kA[q] / Lc;
        split_hl(kn, hh, ll);
        Kh[ix] = hh; Kl[ix] = ll;
        ktph[q] = (short)hh; ktpl[q] = (short)ll;
        split_hl(vA[q], hh, ll);
        vtph[q] = (short)hh; vtpl[q] = (short)ll;
        float dp = rA[q] * uu * kA[q];
        dp += __shfl_xor(dp, 1, 64);
        dp += __shfl_xor(dp, 2, 64);
        dp += __shfl_xor(dp, 4, 64);
        dp += __shfl_xor(dp, 8, 64);
        dp += __shfl_xor(dp, 16, 64);
        dp += __shfl_xor(dp, 32, 64);
        if (lane == 0) diagv[tr] = dp;
      }
      // transposed tiles: row = lane, cols rq..rq+7 (8-aligned, swizzle keeps 16B contiguity)
      const int ixT = lane * 64 + (rq ^ ((lane & 7) << 3));
      *(short8*)&KTh[ixT] = ktph;
      *(short8*)&KTl[ixT] = ktpl;
      *(short8*)&VTh[ixT] = vtph;
      *(short8*)&VTl[ixT] = vtpl;
    }
    __syncthreads();                                  // B2: tiles ready
    // ---------- prefetch next chunk inputs (overwrites dA..vA; last use was 1b) ----------
    if (c + 1 < T_ / 64) {
      const size_t ro = (bT + t0 + 64 + rq) * (size_t)A_ + cb + lane;
#pragma unroll
      for (int q = 0; q < 8; ++q) {
        const size_t o = ro + (size_t)q * A_;
        dA[q] = dec[o];
        rA[q] = bf2f(r[o]);
        if (KF32) kA[q] = k32[o];
        else      kA[q] = bf2f(k16[o]);
        vA[q] = v[o];
      }
    }
    // ---------- merged phase 2+4a: A = R~ K~^T  AND  a4 = V^T K~ (held in regs) ----------
    floatx4 a4[2];
    {
      short8 arh[2], arl[2], avh[2], avl[2];
#pragma unroll
      for (int kst = 0; kst < 2; ++kst) {
        const int c8 = kst * 32 + quad * 8;
        arh[kst] = ldfrag(Rh, mrow + l15, c8);
        arl[kst] = ldfrag(Rl, mrow + l15, c8);
        avh[kst] = ldfrag(VTh, mrow + l15, c8);
        avl[kst] = ldfrag(VTl, mrow + l15, c8);
      }
      floatx4 accA[2];
#pragma unroll
      for (int ni = 0; ni < 2; ++ni) {
        floatx4 z = {0.f, 0.f, 0.f, 0.f};
        accA[ni] = z; a4[ni] = z;
      }
      __builtin_amdgcn_s_setprio(1);
#pragma unroll
      for (int ni = 0; ni < 2; ++ni)
#pragma unroll
        for (int kst = 0; kst < 2; ++kst) {
          const int c8 = kst * 32 + quad * 8;
          short8 bh_ = ldfrag(Kh, mcol + ni * 16 + l15, c8);
          short8 bl_ = ldfrag(Kl, mcol + ni * 16 + l15, c8);
          accA[ni] = __builtin_amdgcn_mfma_f32_16x16x32_bf16(arh[kst], bh_, accA[ni], 0, 0, 0);
          accA[ni] = __builtin_amdgcn_mfma_f32_16x16x32_bf16(arh[kst], bl_, accA[ni], 0, 0, 0);
          accA[ni] = __builtin_amdgcn_mfma_f32_16x16x32_bf16(arl[kst], bh_, accA[ni], 0, 0, 0);
          short8 bkh = ldfrag(KTh, mcol + ni * 16 + l15, c8);
          short8 bkl = ldfrag(KTl, mcol + ni * 16 + l15, c8);
          a4[ni] = __builtin_amdgcn_mfma_f32_16x16x32_bf16(avh[kst], bkh, a4[ni], 0, 0, 0);
          a4[ni] = __builtin_amdgcn_mfma_f32_16x16x32_bf16(avh[kst], bkl, a4[ni], 0, 0, 0);
          a4[ni] = __builtin_amdgcn_mfma_f32_16x16x32_bf16(avl[kst], bkh, a4[ni], 0, 0, 0);
        }
      __builtin_amdgcn_s_setprio(0);
      // A mask + store
#pragma unroll
      for (int ni = 0; ni < 2; ++ni)
#pragma unroll
        for (int vv = 0; vv < 4; ++vv) {
          const int grow = mrow + quad * 4 + vv;
          const int gcol = mcol + ni * 16 + l15;
          float val = (grow > gcol) ? accA[ni][vv] : ((grow == gcol) ? diagv[grow] : 0.f);
          unsigned short hh, ll;
          split_hl(val, hh, ll);
          const int ix = swz(grow, gcol);
          Amh[ix] = hh; Aml[ix] = ll;
        }
    }
    __syncthreads();                                  // B3: Am ready (prefetch drains here)
    // ---------- phase 3: Y = A V + R~ S0 (OLD S), GN*g epilogue ----------
    {
      // g prefetch: thread-private offsets (same thread writes back after B4)
      unsigned short gv[2][4];
#pragma unroll
      for (int ni = 0; ni < 2; ++ni)
#pragma unroll
        for (int vv = 0; vv < 4; ++vv) {
          const size_t off = (bT + t0 + mrow + quad * 4 + vv) * (size_t)A_ + cb + mcol + ni * 16 + l15;
          gv[ni][vv] = gz[off];
        }
      short8 aAh[2], aAl[2], aRh[2], aRl[2];
#pragma unroll
      for (int kst = 0; kst < 2; ++kst) {
        const int c8 = kst * 32 + quad * 8;
        aAh[kst] = ldfrag(Amh, mrow + l15, c8);
        aAl[kst] = ldfrag(Aml, mrow + l15, c8);
        aRh[kst] = ldfrag(Rh, mrow + l15, c8);
        aRl[kst] = ldfrag(Rl, mrow + l15, c8);
      }
      floatx4 acc[2];
#pragma unroll
      for (int ni = 0; ni < 2; ++ni) { floatx4 z = {0.f, 0.f, 0.f, 0.f}; acc[ni] = z; }
      __builtin_amdgcn_s_setprio(1);
#pragma unroll
      for (int ni = 0; ni < 2; ++ni)
#pragma unroll
        for (int kst = 0; kst < 2; ++kst) {
          const int c8 = kst * 32 + quad * 8;
          const int brow = mcol + ni * 16 + l15;
          short8 bvh = ldfrag(VTh, brow, c8);
          short8 bvl = ldfrag(VTl, brow, c8);
          acc[ni] = __builtin_amdgcn_mfma_f32_16x16x32_bf16(aAh[kst], bvh, acc[ni], 0, 0, 0);
          acc[ni] = __builtin_amdgcn_mfma_f32_16x16x32_bf16(aAh[kst], bvl, acc[ni], 0, 0, 0);
          acc[ni] = __builtin_amdgcn_mfma_f32_16x16x32_bf16(aAl[kst], bvh, acc[ni], 0, 0, 0);
          short8 bsh = ldfrag(SThi, brow, c8);
          short8 bsl = ldfrag(STlo, brow, c8);
          acc[ni] = __builtin_amdgcn_mfma_f32_16x16x32_bf16(aRh[kst], bsh, acc[ni], 0, 0, 0);
          acc[ni] = __builtin_amdgcn_mfma_f32_16x16x32_bf16(aRh[kst], bsl, acc[ni], 0, 0, 0);
          acc[ni] = __builtin_amdgcn_mfma_f32_16x16x32_bf16(aRl[kst], bsh, acc[ni], 0, 0, 0);
        }
      __builtin_amdgcn_s_setprio(0);
      // GN partials over this wave's 32 cols; exchange with partner wave (w^1)
      float s1_[4], s2_[4];
#pragma unroll
      for (int vv = 0; vv < 4; ++vv) {
        float s1 = acc[0][vv] + acc[1][vv];
        float s2 = acc[0][vv] * acc[0][vv] + acc[1][vv] * acc[1][vv];
        s1 += __shfl_xor(s1, 1, 64); s2 += __shfl_xor(s2, 1, 64);
        s1 += __shfl_xor(s1, 2, 64); s2 += __shfl_xor(s2, 2, 64);
        s1 += __shfl_xor(s1, 4, 64); s2 += __shfl_xor(s2, 4, 64);
        s1 += __shfl_xor(s1, 8, 64); s2 += __shfl_xor(s2, 8, 64);
        s1_[vv] = s1; s2_[vv] = s2;
        if (l15 == 0) {
          gnp[w][quad * 4 + vv][0] = s1;
          gnp[w][quad * 4 + vv][1] = s2;
        }
      }
      __syncthreads();                                // B4: GN partials ready; all pair reads drained
#pragma unroll
      for (int ni = 0; ni < 2; ++ni)
#pragma unroll
        for (int vv = 0; vv < 4; ++vv) {
          const int rloc = quad * 4 + vv;
          float s1 = s1_[vv] + gnp[w ^ 1][rloc][0];
          float s2 = s2_[vv] + gnp[w ^ 1][rloc][1];
          float mu = s1 * (1.f / 64.f);
          float var = s2 * (1.f / 64.f) - mu * mu;
          float rs = rsqrtf(var + 6.4e-4f);           // EPS = 1e-5 * 64
          const size_t off = (bT + t0 + mrow + rloc) * (size_t)A_ + cb + mcol + ni * 16 + l15;
          float yn = (acc[ni][vv] - mu) * rs * lnwv[ni] + lnbv[ni];
          float z = yn * h2f(gv[ni][vv]);
          gz[off] = f2h(z);
        }
    }
    // ---------- phase 4b (post-B4): S = LcEnd .* (a4 + S_old), per-wave disjoint ----------
    {
#pragma unroll
      for (int ni = 0; ni < 2; ++ni) {
        const float lce = LcEnd[mcol + ni * 16 + l15];
#pragma unroll
        for (int vv = 0; vv < 4; ++vv) {
          const int jr = mrow + quad * 4 + vv;
          const int ic = mcol + ni * 16 + l15;
          const int ix = swz(jr, ic);
          float sold = bf2f(SThi[ix]) + bf2f(STlo[ix]);
          float snew = lce * (a4[ni][vv] + sold);
          unsigned short hh, ll;
          split_hl(snew, hh, ll);
          SThi[ix] = hh; STlo[ix] = ll;
        }
      }
    }
    // no B5: pair writes ordered vs next reads by next B1/B2
  }
}

// ---------------- launch ----------------
extern "C" void kernel_launch(void* const* d_in, const int* in_sizes, int n_in,
                              void* d_out, int out_size, void* d_ws, size_t ws_size,
                              hipStream_t stream) {
  (void)in_sizes; (void)n_in; (void)out_size;
  const float* x   = (const float*)d_in[0];
  const float* tmx = (const float*)d_in[1];
  const float* tmw = (const float*)d_in[2];
  const float* tmk = (const float*)d_in[3];
  const float* tmv = (const float*)d_in[4];
  const float* tmr = (const float*)d_in[5];
  const float* tmg = (const float*)d_in[6];
  const float* w1  = (const float*)d_in[7];   // (C,160)
  const float* w2  = (const float*)d_in[8];   // (5,32,C)
  const float* td  = (const float*)d_in[9];   // (A)
  const float* dw1 = (const float*)d_in[10];  // (C,64)
  const float* dw2 = (const float*)d_in[11];  // (64,A)
  const float* u   = (const float*)d_in[12];  // (H,N)
  const float* Wr  = (const float*)d_in[13];
  const float* Wk  = (const float*)d_in[14];
  const float* Wv  = (const float*)d_in[15];
  const float* Wg  = (const float*)d_in[16];
  const float* Wo  = (const float*)d_in[17];
  const float* lnw = (const float*)d_in[18];
  const float* lnb = (const float*)d_in[19];

  char* ws = (char*)d_ws;
  const size_t MB = 1024 * 1024;
  // 472MB layout (proven safe footprint), lifetime-overlapped:
  // [0,64)    U0: xxx -> g (f16) -> z (f16, in place)
  // [64,72.4)     m5 (f16)
  // [64,192)      vf (v f32, step 8+)
  // [128,192) U2: bxk (w1T scratch at [128,129) pre-mix)
  // [192,256) U3: bxv -> dec lower half
  // [256,320) U4: bxw -> dec upper half     (dec = [192,320) f32)
  // [320,384) U5: bxg -> r (bf16)
  // [384,448) U6: bxr -> k (bf16, L0)
  // [448,456.4)   Wf16 scratch (dw1T pre) -> Wf16 per projection
  // [460,460.7)   w2T (f16; read during mix_gemm only)
  // [464,472)     t1 (f32, 8MB)
  // x16 (67MB, f16 copy of x, live steps 1-3 only) lives in d_out (134MB,
  // fully overwritten at step 11) -> zero workspace cost, no overlap.
  unsigned short* xxx  = (unsigned short*)(ws + 0 * MB);
  unsigned short* gb   = (unsigned short*)(ws + 0 * MB);     // g then z (f16)
  unsigned short* m5   = (unsigned short*)(ws + 64 * MB);    // f16
  float*          vf   = (float*)(ws + 64 * MB);             // v f32 [64,192)
  unsigned short* w1T  = (unsigned short*)(ws + 128 * MB);
  unsigned short* bxk  = (unsigned short*)(ws + 128 * MB);
  unsigned short* bxv  = (unsigned short*)(ws + 192 * MB);
  float*          decb = (float*)(ws + 192 * MB);            // dec f32 [192,320)
  unsigned short* bxw  = (unsigned short*)(ws + 256 * MB);
  unsigned short* bxg  = (unsigned short*)(ws + 320 * MB);
  unsigned short* rb   = (unsigned short*)(ws + 320 * MB);   // r (bf16)
  unsigned short* bxr  = (unsigned short*)(ws + 384 * MB);
  unsigned short* kb   = (unsigned short*)(ws + 384 * MB);   // k bf16 (L0)
  unsigned short* dw1T = (unsigned short*)(ws + 448 * MB);
  unsigned short* Wf   = (unsigned short*)(ws + 448 * MB);   // f16 weight scratch
  unsigned short* w2T  = (unsigned short*)(ws + 460 * MB);   // (5,2048,32) f16
  float*          t1   = (float*)(ws + 464 * MB);
  unsigned short* x16  = (unsigned short*)d_out;             // f16 x copy in d_out scratch
  const bool kf32 = ws_size >= (size_t)616 * MB;
  float* kf = (float*)(ws + 480 * MB);

  const int nW = A_ * C_;  // 4.19M elements
  const size_t EBT = (size_t)BT_ * C_;

  // 1. token-shift mix -> xxx (f16) + x16 (f16 copy, staged in d_out)
  shift_mix<<<(int)(EBT / 4 / 256), 256, 0, stream>>>(x, tmx, xxx, x16);

  // 2. m5 = tanh(xxx @ maa_w1) padded N=256 (f16 out)
  transpose_pad<<<(256 * 2048) / 256, 256, 0, stream>>>(w1, w1T, 256, 160);
  gemm_f16<4><<<dim3(BT_ / 128, 2), 256, 0, stream>>>(xxx, w1T, m5, BT_, 256, 2048);

  // 3. five mixed inputs via MFMA mix, f on blockIdx.z (needs w2T; coalesced epilogue)
  transpose_w2<<<(5 * 65536) / 256, 256, 0, stream>>>(w2, w2T);
  mix_gemm<<<dim3(BT_ / 128, C_ / 128, 5), 256, 0, stream>>>(m5, w2T, x16,
                                                             tmw, tmk, tmv, tmr, tmg,
                                                             bxw, bxk, bxv, bxr, bxg);

  // 4. t1 = tanh(xw @ decay_w1) padded N=128 (f32 out)
  transpose_pad<<<(128 * 2048) / 256, 256, 0, stream>>>(dw1, dw1T, 128, 64);
  gemm_f16<2><<<dim3(BT_ / 128, 1), 256, 0, stream>>>(bxw, dw1T, t1, BT_, 128, 2048);

  // 5-8. projections with f16 weights, 256^2 pipelined GEMM
  conv_f16<<<nW / 256, 256, 0, stream>>>(Wg, Wf, nW);
  gemm256<1><<<dim3(BT_ / 256, C_ / 256), 512, 0, stream>>>(bxg, Wf, gb, BT_, 2048, 2048);
  conv_f16<<<nW / 256, 256, 0, stream>>>(Wr, Wf, nW);
  gemm256<0><<<dim3(BT_ / 256, C_ / 256), 512, 0, stream>>>(bxr, Wf, rb, BT_, 2048, 2048);
  conv_f16<<<nW / 256, 256, 0, stream>>>(Wk, Wf, nW);
  if (kf32) {
    gemm256<3><<<dim3(BT_ / 256, C_ / 256), 512, 0, stream>>>(bxk, Wf, kf, BT_, 2048, 2048);
  } else {
    gemm256<0><<<dim3(BT_ / 256, C_ / 256), 512, 0, stream>>>(bxk, Wf, kb, BT_, 2048, 2048);
  }
  conv_f16<<<nW / 256, 256, 0, stream>>>(Wv, Wf, nW);
  gemm256<3><<<dim3(BT_ / 256, C_ / 256), 512, 0, stream>>>(bxv, Wf, vf, BT_, 2048, 2048);

  // 9. dec (after bxv/bxw are dead; overlays them)
  decay_kernel<<<BT_ / 16, 256, 0, stream>>>(t1, dw2, td, decb);

  // 10. WKV6 chunk-parallel MFMA (8 waves, 4 barriers/chunk) + fused GroupNorm*g
  if (kf32) {
    wkv6_chunk<1><<<256, 512, 0, stream>>>(rb, kb, kf, vf, decb, u, gb, lnw, lnb);
  } else {
    wkv6_chunk<0><<<256, 512, 0, stream>>>(rb, kb, kf, vf, decb, u, gb, lnw, lnb);
  }

  // 11. output projection: z @ Wo^T (both f16) -> d_out (f32, overwrites x16 scratch)
  conv_f16<<<nW / 256, 256, 0, stream>>>(Wo, Wf, nW);
  gemm256<3><<<dim3(BT_ / 256, C_ / 256), 512, 0, stream>>>(gb, Wf, (float*)d_out, BT_, 2048, 2048);
}